// Round 1
// baseline (274.286 us; speedup 1.0000x reference)
//
#include <hip/hip_runtime.h>

#define B_ 32
#define N_ 4096
#define D_ 64
#define C_ 129
#define BC_ 4
#define SLICES_ 8
#define RPS_ (N_ / SLICES_)   // 512 rows per slice

// ---------------------------------------------------------------- counts
__global__ __launch_bounds__(256) void k_counts(const int* __restrict__ cl,
                                                float* __restrict__ counts) {
    __shared__ int cnt[C_];
    int bc = blockIdx.x;
    for (int i = threadIdx.x; i < C_; i += 256) cnt[i] = 0;
    __syncthreads();
    for (int n = threadIdx.x; n < N_; n += 256)
        atomicAdd(&cnt[cl[bc * N_ + n]], 1);
    __syncthreads();
    for (int i = threadIdx.x; i < C_; i += 256)
        counts[bc * C_ + i] = (float)cnt[i];
}

// ---------------------------------------------------------------- segment sums
// grid: B*3*SLICES blocks. Each block: LDS partial [129][64] (stride 65 so
// bank = (c+d)%32 -> random clusters spread over banks), then global atomicAdd.
__global__ __launch_bounds__(256) void k_segsum(const float* __restrict__ q,
                                                const float* __restrict__ k,
                                                const float* __restrict__ v,
                                                const int* __restrict__ cl,
                                                float* __restrict__ sums) {
    __shared__ float acc[C_ * 65];
    int bid = blockIdx.x;
    int s = bid & 7;            // slice
    int t = (bid >> 3) % 3;     // tensor
    int b = bid / 24;           // batch
    const float* src = (t == 0) ? q : (t == 1) ? k : v;
    for (int i = threadIdx.x; i < C_ * 65; i += 256) acc[i] = 0.f;
    __syncthreads();
    const int* g = cl + (b & 3) * N_;
    int d4 = threadIdx.x & 15;  // float4 lane within row
    int r0 = threadIdx.x >> 4;  // 16 rows in flight
    const float4* src4 = (const float4*)(src + (size_t)b * N_ * D_);
    for (int r = r0; r < RPS_; r += 16) {
        int n = s * RPS_ + r;
        float4 val = src4[n * 16 + d4];
        int c = g[n];
        float* a = &acc[c * 65 + d4 * 4];
        atomicAdd(a + 0, val.x);
        atomicAdd(a + 1, val.y);
        atomicAdd(a + 2, val.z);
        atomicAdd(a + 3, val.w);
    }
    __syncthreads();
    float* dst = sums + ((size_t)t * B_ + b) * C_ * D_;
    for (int i = threadIdx.x; i < C_ * D_; i += 256)
        atomicAdd(dst + i, acc[(i >> 6) * 65 + (i & 63)]);
}

// ---------------------------------------------------------------- attention over centers
// grid: B * 9 blocks (16 q-rows per block, last block 1 row). 256 threads.
__global__ __launch_bounds__(256) void k_attn(const float* __restrict__ sums,
                                              const float* __restrict__ counts,
                                              float* __restrict__ vout,
                                              float* __restrict__ aout) {
    __shared__ float4 kc4[C_ * 17];   // K centers, 16 data float4 + 1 pad
    __shared__ float4 vc4[C_ * 17];   // V centers
    __shared__ float4 qr4[16 * 16];   // this block's Q rows
    __shared__ float cnt_s[C_];
    __shared__ float w_s[C_];
    __shared__ float arow[4][4][132]; // per-wave A rows (k=0..128, pad to 132)

    int b = blockIdx.x / 9;
    int qg = blockIdx.x % 9;
    int q0 = qg * 16;
    int qcnt = min(16, C_ - q0);
    int tid = threadIdx.x;

    for (int i = tid; i < C_; i += 256) {
        float c = counts[(b & 3) * C_ + i];
        cnt_s[i] = c;
        w_s[i] = (c > 0.f) ? 1.f / c : 0.f;
    }
    __syncthreads();

    const float4* qsum4 = (const float4*)(sums + (size_t)b * C_ * D_);
    const float4* ksum4 = (const float4*)(sums + ((size_t)B_ + b) * C_ * D_);
    const float4* vsum4 = (const float4*)(sums + ((size_t)2 * B_ + b) * C_ * D_);

    for (int i = tid; i < C_ * 16; i += 256) {
        int c = i >> 4, d4 = i & 15;
        float w = w_s[c];
        float4 kv = ksum4[i];
        float4 vv = vsum4[i];
        kv.x *= w; kv.y *= w; kv.z *= w; kv.w *= w;
        vv.x *= w; vv.y *= w; vv.z *= w; vv.w *= w;
        kc4[c * 17 + d4] = kv;
        vc4[c * 17 + d4] = vv;
    }
    for (int i = tid; i < qcnt * 16; i += 256) {
        int r = i >> 4, d4 = i & 15;
        float w = w_s[q0 + r];
        float4 qv = qsum4[(q0 + r) * 16 + d4];
        qv.x *= w; qv.y *= w; qv.z *= w; qv.w *= w;
        qr4[i] = qv;
    }
    __syncthreads();

    int wave = tid >> 6, lane = tid & 63;

    for (int tt = wave; tt * 4 < qcnt; tt += 4) {
        int t4 = tt * 4;
        // ---- QK: 4 q-rows x (k=lane, k=lane+64, k=128)
        float s0[4] = {0, 0, 0, 0}, s1[4] = {0, 0, 0, 0}, s2[4] = {0, 0, 0, 0};
        for (int d4 = 0; d4 < 16; d4++) {
            float4 kv0 = kc4[lane * 17 + d4];
            float4 kv1 = kc4[(lane + 64) * 17 + d4];
            float4 kv2 = kc4[128 * 17 + d4];
#pragma unroll
            for (int r = 0; r < 4; r++) {
                int rr = t4 + r; if (rr >= qcnt) rr = qcnt - 1;
                float4 qv = qr4[rr * 16 + d4];
                s0[r] += qv.x * kv0.x + qv.y * kv0.y + qv.z * kv0.z + qv.w * kv0.w;
                s1[r] += qv.x * kv1.x + qv.y * kv1.y + qv.z * kv1.z + qv.w * kv1.w;
                s2[r] += qv.x * kv2.x + qv.y * kv2.y + qv.z * kv2.z + qv.w * kv2.w;
            }
        }
        // ---- softmax (weighted by counts, renormalized)
#pragma unroll
        for (int r = 0; r < 4; r++) {
            if (t4 + r >= qcnt) break;
            int qrow = q0 + t4 + r;
            float m = fmaxf(s0[r], s1[r]);
            if (lane == 0) m = fmaxf(m, s2[r]);
            for (int off = 32; off > 0; off >>= 1)
                m = fmaxf(m, __shfl_xor(m, off, 64));
            float e0 = __expf(s0[r] - m) * cnt_s[lane];
            float e1 = __expf(s1[r] - m) * cnt_s[lane + 64];
            float e2 = (lane == 0) ? __expf(s2[r] - m) * cnt_s[128] : 0.f;
            float sum = e0 + e1 + e2;
            for (int off = 32; off > 0; off >>= 1)
                sum += __shfl_xor(sum, off, 64);
            float inv = 1.f / sum;
            float a0 = e0 * inv, a1 = e1 * inv;
            arow[wave][r][lane] = a0;
            arow[wave][r][64 + lane] = a1;
            if (lane == 0) {
                arow[wave][r][128] = e2 * inv;
                aout[b * C_ + qrow] = a0;   // A_full[:, :, 0]
            }
        }
        __builtin_amdgcn_s_waitcnt(0);  // ensure arow writes visible in-wave
        // ---- V product: lane = (row within tile, d4)
        int rr = lane >> 4, d4 = lane & 15;
        const float4* ar4 = (const float4*)arow[wave][rr];
        float4 o = make_float4(0.f, 0.f, 0.f, 0.f);
        for (int k4 = 0; k4 < 32; k4++) {
            float4 a4 = ar4[k4];
            float4 v0 = vc4[(k4 * 4 + 0) * 17 + d4];
            float4 v1 = vc4[(k4 * 4 + 1) * 17 + d4];
            float4 v2 = vc4[(k4 * 4 + 2) * 17 + d4];
            float4 v3 = vc4[(k4 * 4 + 3) * 17 + d4];
            o.x += a4.x * v0.x + a4.y * v1.x + a4.z * v2.x + a4.w * v3.x;
            o.y += a4.x * v0.y + a4.y * v1.y + a4.z * v2.y + a4.w * v3.y;
            o.z += a4.x * v0.z + a4.y * v1.z + a4.z * v2.z + a4.w * v3.z;
            o.w += a4.x * v0.w + a4.y * v1.w + a4.z * v2.w + a4.w * v3.w;
        }
        {
            float a128 = arow[wave][rr][128];
            float4 vv = vc4[128 * 17 + d4];
            o.x += a128 * vv.x; o.y += a128 * vv.y;
            o.z += a128 * vv.z; o.w += a128 * vv.w;
        }
        if (t4 + rr < qcnt) {
            float4* dst = (float4*)(vout + ((size_t)b * C_ + (q0 + t4 + rr)) * D_);
            dst[d4] = o;
        }
    }
}

// ---------------------------------------------------------------- gather
__global__ __launch_bounds__(256) void k_gather(const float* __restrict__ vout,
                                                const int* __restrict__ cl,
                                                float* __restrict__ out) {
    int idx = blockIdx.x * 256 + threadIdx.x;   // over B*N*16 float4s
    int d4 = idx & 15;
    int n = (idx >> 4) & (N_ - 1);
    int b = idx >> 16;
    int c = cl[(b & 3) * N_ + n];
    const float4* src = (const float4*)(vout + ((size_t)b * C_ + c) * D_);
    ((float4*)out)[idx] = src[d4];
}

// ---------------------------------------------------------------- launch
extern "C" void kernel_launch(void* const* d_in, const int* in_sizes, int n_in,
                              void* d_out, int out_size, void* d_ws, size_t ws_size,
                              hipStream_t stream) {
    const float* q = (const float*)d_in[0];
    const float* k = (const float*)d_in[1];
    const float* v = (const float*)d_in[2];
    const int* cl = (const int*)d_in[3];
    float* out = (float*)d_out;
    float* aout = out + (size_t)B_ * N_ * D_;   // A_full[:, :, 0] tail

    float* ws = (float*)d_ws;
    float* counts = ws;                                   // [4][129]
    float* sums = ws + 1024;                              // [3][B][C][D]
    float* vout = ws + 1024 + (size_t)3 * B_ * C_ * D_;   // [B][C][D]

    // sums are accumulated with global atomics -> must be zeroed (ws is poisoned)
    hipMemsetAsync(sums, 0, (size_t)3 * B_ * C_ * D_ * sizeof(float), stream);

    k_counts<<<BC_, 256, 0, stream>>>(cl, counts);
    k_segsum<<<B_ * 3 * SLICES_, 256, 0, stream>>>(q, k, v, cl, sums);
    k_attn<<<B_ * 9, 256, 0, stream>>>(sums, counts, vout, aout);
    k_gather<<<(B_ * N_ * 16) / 256, 256, 0, stream>>>(vout, cl, out);
}

// Round 2
// 175.168 us; speedup vs baseline: 1.5658x; 1.5658x over previous
//
#include <hip/hip_runtime.h>

#define B_ 32
#define N_ 4096
#define D_ 64
#define C_ 129
#define BC_ 4
#define CG_ 33   // ceil(C_/4) cluster-groups, 4 waves/block = 4 clusters/block

// ---------------------------------------------------------------- counting sort
// One block per cluster-batch row. Produces counts (float), offsets [C_+1],
// and sidx: row indices sorted by cluster (order within cluster arbitrary).
__global__ __launch_bounds__(256) void k_sort(const int* __restrict__ cl,
                                              float* __restrict__ counts,
                                              int* __restrict__ offsets,
                                              int* __restrict__ sidx) {
    __shared__ int cnt[C_];
    __shared__ int base[C_ + 1];
    __shared__ int cur[C_];
    int bc = blockIdx.x, tid = threadIdx.x;
    for (int i = tid; i < C_; i += 256) { cnt[i] = 0; cur[i] = 0; }
    __syncthreads();
    const int* g = cl + bc * N_;
    for (int n = tid; n < N_; n += 256) atomicAdd(&cnt[g[n]], 1);
    __syncthreads();
    if (tid == 0) {
        int acc = 0;
        for (int c = 0; c < C_; c++) { base[c] = acc; acc += cnt[c]; }
        base[C_] = acc;
    }
    __syncthreads();
    for (int i = tid; i < C_; i += 256) {
        counts[bc * C_ + i] = (float)cnt[i];
        offsets[bc * (C_ + 1) + i] = base[i];
    }
    if (tid == 0) offsets[bc * (C_ + 1) + C_] = N_;
    for (int n = tid; n < N_; n += 256) {
        int c = g[n];
        int pos = base[c] + atomicAdd(&cur[c], 1);
        sidx[bc * N_ + pos] = n;
    }
}

// ---------------------------------------------------------------- segment sums (sorted)
// One wave per (b, tensor, cluster). Wave gathers 4 rows/iter (lane = sub*16+d4),
// register-accumulates, xor-shuffle reduces across the 4 row-subgroups, writes
// the center once, pre-scaled by 1/count. No atomics anywhere.
__global__ __launch_bounds__(256) void k_segsum2(const float* __restrict__ q,
                                                 const float* __restrict__ k,
                                                 const float* __restrict__ v,
                                                 const int* __restrict__ offsets,
                                                 const int* __restrict__ sidx,
                                                 float* __restrict__ sums) {
    int bid = blockIdx.x;
    int cg = bid % CG_;
    int t = (bid / CG_) % 3;
    int b = bid / (CG_ * 3);
    int wave = threadIdx.x >> 6, lane = threadIdx.x & 63;
    int c = cg * 4 + wave;
    if (c >= C_) return;
    int bc = b & 3;
    int start = offsets[bc * (C_ + 1) + c];
    int end = offsets[bc * (C_ + 1) + c + 1];
    const float* src = (t == 0) ? q : (t == 1) ? k : v;
    const float4* src4 = (const float4*)(src + (size_t)b * N_ * D_);
    const int* si = sidx + bc * N_;
    int sub = lane >> 4, d4 = lane & 15;
    float4 acc = make_float4(0.f, 0.f, 0.f, 0.f);
    for (int i = start + sub; i < end; i += 4) {
        int row = si[i];
        float4 val = src4[row * 16 + d4];
        acc.x += val.x; acc.y += val.y; acc.z += val.z; acc.w += val.w;
    }
    for (int off = 16; off <= 32; off <<= 1) {
        acc.x += __shfl_xor(acc.x, off, 64);
        acc.y += __shfl_xor(acc.y, off, 64);
        acc.z += __shfl_xor(acc.z, off, 64);
        acc.w += __shfl_xor(acc.w, off, 64);
    }
    int cnt = end - start;
    float w = (cnt > 0) ? 1.f / (float)cnt : 0.f;
    if (sub == 0) {
        float4 o = make_float4(acc.x * w, acc.y * w, acc.z * w, acc.w * w);
        ((float4*)(sums + ((size_t)t * B_ + b) * C_ * D_))[c * 16 + d4] = o;
    }
}

// ---------------------------------------------------------------- attention over centers
// grid: B * 9 blocks (16 q-rows per block, last block 1 row). 256 threads.
// Centers arrive pre-scaled by 1/count.
__global__ __launch_bounds__(256) void k_attn(const float* __restrict__ sums,
                                              const float* __restrict__ counts,
                                              float* __restrict__ vout,
                                              float* __restrict__ aout) {
    __shared__ float4 kc4[C_ * 17];   // K centers, 16 data float4 + 1 pad
    __shared__ float4 vc4[C_ * 17];   // V centers
    __shared__ float4 qr4[16 * 16];   // this block's Q rows
    __shared__ float cnt_s[C_];
    __shared__ float arow[4][4][132]; // per-wave A rows (k=0..128, pad to 132)

    int b = blockIdx.x / 9;
    int qg = blockIdx.x % 9;
    int q0 = qg * 16;
    int qcnt = min(16, C_ - q0);
    int tid = threadIdx.x;

    for (int i = tid; i < C_; i += 256)
        cnt_s[i] = counts[(b & 3) * C_ + i];
    __syncthreads();

    const float4* qsum4 = (const float4*)(sums + (size_t)b * C_ * D_);
    const float4* ksum4 = (const float4*)(sums + ((size_t)B_ + b) * C_ * D_);
    const float4* vsum4 = (const float4*)(sums + ((size_t)2 * B_ + b) * C_ * D_);

    for (int i = tid; i < C_ * 16; i += 256) {
        int c = i >> 4, d4 = i & 15;
        kc4[c * 17 + d4] = ksum4[i];
        vc4[c * 17 + d4] = vsum4[i];
    }
    for (int i = tid; i < qcnt * 16; i += 256) {
        int r = i >> 4, d4 = i & 15;
        qr4[i] = qsum4[(q0 + r) * 16 + d4];
    }
    __syncthreads();

    int wave = tid >> 6, lane = tid & 63;

    for (int tt = wave; tt * 4 < qcnt; tt += 4) {
        int t4 = tt * 4;
        // ---- QK: 4 q-rows x (k=lane, k=lane+64, k=128)
        float s0[4] = {0, 0, 0, 0}, s1[4] = {0, 0, 0, 0}, s2[4] = {0, 0, 0, 0};
        for (int d4 = 0; d4 < 16; d4++) {
            float4 kv0 = kc4[lane * 17 + d4];
            float4 kv1 = kc4[(lane + 64) * 17 + d4];
            float4 kv2 = kc4[128 * 17 + d4];
#pragma unroll
            for (int r = 0; r < 4; r++) {
                int rr = t4 + r; if (rr >= qcnt) rr = qcnt - 1;
                float4 qv = qr4[rr * 16 + d4];
                s0[r] += qv.x * kv0.x + qv.y * kv0.y + qv.z * kv0.z + qv.w * kv0.w;
                s1[r] += qv.x * kv1.x + qv.y * kv1.y + qv.z * kv1.z + qv.w * kv1.w;
                s2[r] += qv.x * kv2.x + qv.y * kv2.y + qv.z * kv2.z + qv.w * kv2.w;
            }
        }
        // ---- softmax (weighted by counts, renormalized)
#pragma unroll
        for (int r = 0; r < 4; r++) {
            if (t4 + r >= qcnt) break;
            int qrow = q0 + t4 + r;
            float m = fmaxf(s0[r], s1[r]);
            if (lane == 0) m = fmaxf(m, s2[r]);
            for (int off = 32; off > 0; off >>= 1)
                m = fmaxf(m, __shfl_xor(m, off, 64));
            float e0 = __expf(s0[r] - m) * cnt_s[lane];
            float e1 = __expf(s1[r] - m) * cnt_s[lane + 64];
            float e2 = (lane == 0) ? __expf(s2[r] - m) * cnt_s[128] : 0.f;
            float sum = e0 + e1 + e2;
            for (int off = 32; off > 0; off >>= 1)
                sum += __shfl_xor(sum, off, 64);
            float inv = 1.f / sum;
            float a0 = e0 * inv, a1 = e1 * inv;
            arow[wave][r][lane] = a0;
            arow[wave][r][64 + lane] = a1;
            if (lane == 0) {
                arow[wave][r][128] = e2 * inv;
                aout[b * C_ + qrow] = a0;   // A_full[:, :, 0]
            }
        }
        __builtin_amdgcn_s_waitcnt(0);  // ensure arow writes visible in-wave
        // ---- V product: lane = (row within tile, d4)
        int rr = lane >> 4, d4 = lane & 15;
        const float4* ar4 = (const float4*)arow[wave][rr];
        float4 o = make_float4(0.f, 0.f, 0.f, 0.f);
        for (int k4 = 0; k4 < 32; k4++) {
            float4 a4 = ar4[k4];
            float4 v0 = vc4[(k4 * 4 + 0) * 17 + d4];
            float4 v1 = vc4[(k4 * 4 + 1) * 17 + d4];
            float4 v2 = vc4[(k4 * 4 + 2) * 17 + d4];
            float4 v3 = vc4[(k4 * 4 + 3) * 17 + d4];
            o.x += a4.x * v0.x + a4.y * v1.x + a4.z * v2.x + a4.w * v3.x;
            o.y += a4.x * v0.y + a4.y * v1.y + a4.z * v2.y + a4.w * v3.y;
            o.z += a4.x * v0.z + a4.y * v1.z + a4.z * v2.z + a4.w * v3.z;
            o.w += a4.x * v0.w + a4.y * v1.w + a4.z * v2.w + a4.w * v3.w;
        }
        {
            float a128 = arow[wave][rr][128];
            float4 vv = vc4[128 * 17 + d4];
            o.x += a128 * vv.x; o.y += a128 * vv.y;
            o.z += a128 * vv.z; o.w += a128 * vv.w;
        }
        if (t4 + rr < qcnt) {
            float4* dst = (float4*)(vout + ((size_t)b * C_ + (q0 + t4 + rr)) * D_);
            dst[d4] = o;
        }
    }
}

// ---------------------------------------------------------------- gather
__global__ __launch_bounds__(256) void k_gather(const float* __restrict__ vout,
                                                const int* __restrict__ cl,
                                                float* __restrict__ out) {
    int idx = blockIdx.x * 256 + threadIdx.x;   // over B*N*16 float4s
    int d4 = idx & 15;
    int n = (idx >> 4) & (N_ - 1);
    int b = idx >> 16;
    int c = cl[(b & 3) * N_ + n];
    const float4* src = (const float4*)(vout + ((size_t)b * C_ + c) * D_);
    ((float4*)out)[idx] = src[d4];
}

// ---------------------------------------------------------------- launch
extern "C" void kernel_launch(void* const* d_in, const int* in_sizes, int n_in,
                              void* d_out, int out_size, void* d_ws, size_t ws_size,
                              hipStream_t stream) {
    const float* q = (const float*)d_in[0];
    const float* k = (const float*)d_in[1];
    const float* v = (const float*)d_in[2];
    const int* cl = (const int*)d_in[3];
    float* out = (float*)d_out;
    float* aout = out + (size_t)B_ * N_ * D_;   // A_full[:, :, 0] tail

    float* ws = (float*)d_ws;
    float* counts = ws;                                   // [4][C_] (pad to 1024)
    float* sums = ws + 1024;                              // [3][B_][C_][D_] pre-scaled centers
    float* vout = sums + (size_t)3 * B_ * C_ * D_;        // [B_][C_][D_]
    int* offsets = (int*)(vout + (size_t)B_ * C_ * D_);   // [4][C_+1]
    int* sidx = offsets + 4 * (C_ + 1);                   // [4][N_]

    k_sort<<<BC_, 256, 0, stream>>>(cl, counts, offsets, sidx);
    k_segsum2<<<B_ * 3 * CG_, 256, 0, stream>>>(q, k, v, offsets, sidx, sums);
    k_attn<<<B_ * 9, 256, 0, stream>>>(sums, counts, vout, aout);
    k_gather<<<(B_ * N_ * 16) / 256, 256, 0, stream>>>(vout, cl, out);
}

// Round 3
// 172.366 us; speedup vs baseline: 1.5913x; 1.0163x over previous
//
#include <hip/hip_runtime.h>

#define B_ 32
#define N_ 4096
#define D_ 64
#define C_ 129
#define BC_ 4
#define CG_ 33   // ceil(C_/4): 4 waves/block = 4 clusters/block

// ---------------------------------------------------------------- counting sort
// One block per cluster-batch row. Produces counts (float), offsets [C_+1],
// and sidx: row indices sorted by cluster (order within cluster arbitrary).
__global__ __launch_bounds__(256) void k_sort(const int* __restrict__ cl,
                                              float* __restrict__ counts,
                                              int* __restrict__ offsets,
                                              int* __restrict__ sidx) {
    __shared__ int cnt[C_];
    __shared__ int base[C_];
    __shared__ int cur[C_];
    int bc = blockIdx.x, tid = threadIdx.x;
    for (int i = tid; i < C_; i += 256) { cnt[i] = 0; cur[i] = 0; }
    __syncthreads();
    const int* g = cl + bc * N_;
    for (int n = tid; n < N_; n += 256) atomicAdd(&cnt[g[n]], 1);
    __syncthreads();
    // parallel exclusive prefix: thread t sums cnt[0..t) (C is tiny)
    if (tid < C_) {
        int acc = 0;
        for (int i = 0; i < tid; i++) acc += cnt[i];
        base[tid] = acc;
    }
    __syncthreads();
    for (int i = tid; i < C_; i += 256) {
        counts[bc * C_ + i] = (float)cnt[i];
        offsets[bc * (C_ + 1) + i] = base[i];
    }
    if (tid == 0) offsets[bc * (C_ + 1) + C_] = N_;
    for (int n = tid; n < N_; n += 256) {
        int c = g[n];
        int pos = base[c] + atomicAdd(&cur[c], 1);
        sidx[bc * N_ + pos] = n;
    }
}

// ---------------------------------------------------------------- fused segment sums
// One wave per (b, cluster); handles Q, K and V together. 16 rows in flight
// per tensor per iteration (lane = sub*16 + d4, sub covers 4 rows, 4 row-sets
// unrolled) -> 12 independent 1KB wave-gathers outstanding. Tail rows are
// clamped to a valid index and masked by multiply. Centers written once,
// pre-scaled by 1/count. No atomics.
__global__ __launch_bounds__(256) void k_segsum3(const float* __restrict__ q,
                                                 const float* __restrict__ k,
                                                 const float* __restrict__ v,
                                                 const int* __restrict__ offsets,
                                                 const int* __restrict__ sidx,
                                                 float* __restrict__ sums) {
    int bid = blockIdx.x;
    int cg = bid % CG_;
    int b = bid / CG_;
    int wave = threadIdx.x >> 6, lane = threadIdx.x & 63;
    int c = cg * 4 + wave;
    if (c >= C_) return;
    int bc = b & 3;
    int start = offsets[bc * (C_ + 1) + c];
    int end = offsets[bc * (C_ + 1) + c + 1];
    int cnt = end - start;
    int sub = lane >> 4, d4 = lane & 15;

    const float4* q4 = (const float4*)(q + (size_t)b * N_ * D_);
    const float4* k4 = (const float4*)(k + (size_t)b * N_ * D_);
    const float4* v4 = (const float4*)(v + (size_t)b * N_ * D_);
    const int* si = sidx + bc * N_;

    float4 aq = make_float4(0.f, 0.f, 0.f, 0.f);
    float4 ak = make_float4(0.f, 0.f, 0.f, 0.f);
    float4 av = make_float4(0.f, 0.f, 0.f, 0.f);

    if (cnt > 0) {
        int last = end - 1;
        for (int i0 = start; i0 < end; i0 += 16) {
            int ia = i0 + sub, ib = ia + 4, ic = ia + 8, id = ia + 12;
            int ra = si[min(ia, last)];
            int rb = si[min(ib, last)];
            int rc = si[min(ic, last)];
            int rd = si[min(id, last)];
            float ma = (ia < end) ? 1.f : 0.f;
            float mb = (ib < end) ? 1.f : 0.f;
            float mc = (ic < end) ? 1.f : 0.f;
            float md = (id < end) ? 1.f : 0.f;
            float4 qa = q4[ra * 16 + d4], qb = q4[rb * 16 + d4];
            float4 qc = q4[rc * 16 + d4], qd = q4[rd * 16 + d4];
            float4 ka = k4[ra * 16 + d4], kb = k4[rb * 16 + d4];
            float4 kc = k4[rc * 16 + d4], kd = k4[rd * 16 + d4];
            float4 va = v4[ra * 16 + d4], vb = v4[rb * 16 + d4];
            float4 vc = v4[rc * 16 + d4], vd = v4[rd * 16 + d4];
            aq.x += ma * qa.x + mb * qb.x + mc * qc.x + md * qd.x;
            aq.y += ma * qa.y + mb * qb.y + mc * qc.y + md * qd.y;
            aq.z += ma * qa.z + mb * qb.z + mc * qc.z + md * qd.z;
            aq.w += ma * qa.w + mb * qb.w + mc * qc.w + md * qd.w;
            ak.x += ma * ka.x + mb * kb.x + mc * kc.x + md * kd.x;
            ak.y += ma * ka.y + mb * kb.y + mc * kc.y + md * kd.y;
            ak.z += ma * ka.z + mb * kb.z + mc * kc.z + md * kd.z;
            ak.w += ma * ka.w + mb * kb.w + mc * kc.w + md * kd.w;
            av.x += ma * va.x + mb * vb.x + mc * vc.x + md * vd.x;
            av.y += ma * va.y + mb * vb.y + mc * vc.y + md * vd.y;
            av.z += ma * va.z + mb * vb.z + mc * vc.z + md * vd.z;
            av.w += ma * va.w + mb * vb.w + mc * vc.w + md * vd.w;
        }
    }
#pragma unroll
    for (int off = 16; off <= 32; off <<= 1) {
        aq.x += __shfl_xor(aq.x, off, 64); aq.y += __shfl_xor(aq.y, off, 64);
        aq.z += __shfl_xor(aq.z, off, 64); aq.w += __shfl_xor(aq.w, off, 64);
        ak.x += __shfl_xor(ak.x, off, 64); ak.y += __shfl_xor(ak.y, off, 64);
        ak.z += __shfl_xor(ak.z, off, 64); ak.w += __shfl_xor(ak.w, off, 64);
        av.x += __shfl_xor(av.x, off, 64); av.y += __shfl_xor(av.y, off, 64);
        av.z += __shfl_xor(av.z, off, 64); av.w += __shfl_xor(av.w, off, 64);
    }
    if (sub == 0) {
        float w = (cnt > 0) ? 1.f / (float)cnt : 0.f;
        float4 oq = make_float4(aq.x * w, aq.y * w, aq.z * w, aq.w * w);
        float4 ok = make_float4(ak.x * w, ak.y * w, ak.z * w, ak.w * w);
        float4 ov = make_float4(av.x * w, av.y * w, av.z * w, av.w * w);
        ((float4*)(sums + (size_t)b * C_ * D_))[c * 16 + d4] = oq;
        ((float4*)(sums + ((size_t)B_ + b) * C_ * D_))[c * 16 + d4] = ok;
        ((float4*)(sums + ((size_t)2 * B_ + b) * C_ * D_))[c * 16 + d4] = ov;
    }
}

// ---------------------------------------------------------------- attention over centers
// grid: B * 9 blocks (16 q-rows per block, last block 1 row). 256 threads.
// Centers arrive pre-scaled by 1/count.
__global__ __launch_bounds__(256) void k_attn(const float* __restrict__ sums,
                                              const float* __restrict__ counts,
                                              float* __restrict__ vout,
                                              float* __restrict__ aout) {
    __shared__ float4 kc4[C_ * 17];   // K centers, 16 data float4 + 1 pad
    __shared__ float4 vc4[C_ * 17];   // V centers
    __shared__ float4 qr4[16 * 16];   // this block's Q rows
    __shared__ float cnt_s[C_];
    __shared__ float arow[4][4][132]; // per-wave A rows (k=0..128, pad to 132)

    int b = blockIdx.x / 9;
    int qg = blockIdx.x % 9;
    int q0 = qg * 16;
    int qcnt = min(16, C_ - q0);
    int tid = threadIdx.x;

    for (int i = tid; i < C_; i += 256)
        cnt_s[i] = counts[(b & 3) * C_ + i];
    __syncthreads();

    const float4* qsum4 = (const float4*)(sums + (size_t)b * C_ * D_);
    const float4* ksum4 = (const float4*)(sums + ((size_t)B_ + b) * C_ * D_);
    const float4* vsum4 = (const float4*)(sums + ((size_t)2 * B_ + b) * C_ * D_);

    for (int i = tid; i < C_ * 16; i += 256) {
        int c = i >> 4, d4 = i & 15;
        kc4[c * 17 + d4] = ksum4[i];
        vc4[c * 17 + d4] = vsum4[i];
    }
    for (int i = tid; i < qcnt * 16; i += 256) {
        int r = i >> 4, d4 = i & 15;
        qr4[i] = qsum4[(q0 + r) * 16 + d4];
    }
    __syncthreads();

    int wave = tid >> 6, lane = tid & 63;

    for (int tt = wave; tt * 4 < qcnt; tt += 4) {
        int t4 = tt * 4;
        // ---- QK: 4 q-rows x (k=lane, k=lane+64, k=128)
        float s0[4] = {0, 0, 0, 0}, s1[4] = {0, 0, 0, 0}, s2[4] = {0, 0, 0, 0};
        for (int d4 = 0; d4 < 16; d4++) {
            float4 kv0 = kc4[lane * 17 + d4];
            float4 kv1 = kc4[(lane + 64) * 17 + d4];
            float4 kv2 = kc4[128 * 17 + d4];
#pragma unroll
            for (int r = 0; r < 4; r++) {
                int rr = t4 + r; if (rr >= qcnt) rr = qcnt - 1;
                float4 qv = qr4[rr * 16 + d4];
                s0[r] += qv.x * kv0.x + qv.y * kv0.y + qv.z * kv0.z + qv.w * kv0.w;
                s1[r] += qv.x * kv1.x + qv.y * kv1.y + qv.z * kv1.z + qv.w * kv1.w;
                s2[r] += qv.x * kv2.x + qv.y * kv2.y + qv.z * kv2.z + qv.w * kv2.w;
            }
        }
        // ---- softmax (weighted by counts, renormalized)
#pragma unroll
        for (int r = 0; r < 4; r++) {
            if (t4 + r >= qcnt) break;
            int qrow = q0 + t4 + r;
            float m = fmaxf(s0[r], s1[r]);
            if (lane == 0) m = fmaxf(m, s2[r]);
            for (int off = 32; off > 0; off >>= 1)
                m = fmaxf(m, __shfl_xor(m, off, 64));
            float e0 = __expf(s0[r] - m) * cnt_s[lane];
            float e1 = __expf(s1[r] - m) * cnt_s[lane + 64];
            float e2 = (lane == 0) ? __expf(s2[r] - m) * cnt_s[128] : 0.f;
            float sum = e0 + e1 + e2;
            for (int off = 32; off > 0; off >>= 1)
                sum += __shfl_xor(sum, off, 64);
            float inv = 1.f / sum;
            float a0 = e0 * inv, a1 = e1 * inv;
            arow[wave][r][lane] = a0;
            arow[wave][r][64 + lane] = a1;
            if (lane == 0) {
                arow[wave][r][128] = e2 * inv;
                aout[b * C_ + qrow] = a0;   // A_full[:, :, 0]
            }
        }
        __builtin_amdgcn_s_waitcnt(0);  // ensure arow writes visible in-wave
        // ---- V product: lane = (row within tile, d4)
        int rr = lane >> 4, d4 = lane & 15;
        const float4* ar4 = (const float4*)arow[wave][rr];
        float4 o = make_float4(0.f, 0.f, 0.f, 0.f);
        for (int k4 = 0; k4 < 32; k4++) {
            float4 a4 = ar4[k4];
            float4 v0 = vc4[(k4 * 4 + 0) * 17 + d4];
            float4 v1 = vc4[(k4 * 4 + 1) * 17 + d4];
            float4 v2 = vc4[(k4 * 4 + 2) * 17 + d4];
            float4 v3 = vc4[(k4 * 4 + 3) * 17 + d4];
            o.x += a4.x * v0.x + a4.y * v1.x + a4.z * v2.x + a4.w * v3.x;
            o.y += a4.x * v0.y + a4.y * v1.y + a4.z * v2.y + a4.w * v3.y;
            o.z += a4.x * v0.z + a4.y * v1.z + a4.z * v2.z + a4.w * v3.z;
            o.w += a4.x * v0.w + a4.y * v1.w + a4.z * v2.w + a4.w * v3.w;
        }
        {
            float a128 = arow[wave][rr][128];
            float4 vv = vc4[128 * 17 + d4];
            o.x += a128 * vv.x; o.y += a128 * vv.y;
            o.z += a128 * vv.z; o.w += a128 * vv.w;
        }
        if (t4 + rr < qcnt) {
            float4* dst = (float4*)(vout + ((size_t)b * C_ + (q0 + t4 + rr)) * D_);
            dst[d4] = o;
        }
    }
}

// ---------------------------------------------------------------- gather
__global__ __launch_bounds__(256) void k_gather(const float* __restrict__ vout,
                                                const int* __restrict__ cl,
                                                float* __restrict__ out) {
    int idx = blockIdx.x * 256 + threadIdx.x;   // over B*N*16 float4s
    int d4 = idx & 15;
    int n = (idx >> 4) & (N_ - 1);
    int b = idx >> 16;
    int c = cl[(b & 3) * N_ + n];
    const float4* src = (const float4*)(vout + ((size_t)b * C_ + c) * D_);
    ((float4*)out)[idx] = src[d4];
}

// ---------------------------------------------------------------- launch
extern "C" void kernel_launch(void* const* d_in, const int* in_sizes, int n_in,
                              void* d_out, int out_size, void* d_ws, size_t ws_size,
                              hipStream_t stream) {
    const float* q = (const float*)d_in[0];
    const float* k = (const float*)d_in[1];
    const float* v = (const float*)d_in[2];
    const int* cl = (const int*)d_in[3];
    float* out = (float*)d_out;
    float* aout = out + (size_t)B_ * N_ * D_;   // A_full[:, :, 0] tail

    float* ws = (float*)d_ws;
    float* counts = ws;                                   // [4][C_] (pad to 1024)
    float* sums = ws + 1024;                              // [3][B_][C_][D_] pre-scaled centers
    float* vout = sums + (size_t)3 * B_ * C_ * D_;        // [B_][C_][D_]
    int* offsets = (int*)(vout + (size_t)B_ * C_ * D_);   // [4][C_+1]
    int* sidx = offsets + 4 * (C_ + 1);                   // [4][N_]

    k_sort<<<BC_, 256, 0, stream>>>(cl, counts, offsets, sidx);
    k_segsum3<<<B_ * CG_, 256, 0, stream>>>(q, k, v, offsets, sidx, sums);
    k_attn<<<B_ * 9, 256, 0, stream>>>(sums, counts, vout, aout);
    k_gather<<<(B_ * N_ * 16) / 256, 256, 0, stream>>>(vout, cl, out);
}

// Round 4
// 170.180 us; speedup vs baseline: 1.6117x; 1.0128x over previous
//
#include <hip/hip_runtime.h>

#define B_ 32
#define N_ 4096
#define D_ 64
#define C_ 129
#define BC_ 4
#define CG_ 33   // ceil(C_/4): 4 waves/block = 4 clusters/block

// ---------------------------------------------------------------- counting sort
// One block per cluster-batch row. Produces counts (float), offsets [C_+1],
// and sidx: row indices sorted by cluster (order within cluster arbitrary).
__global__ __launch_bounds__(256) void k_sort(const int* __restrict__ cl,
                                              float* __restrict__ counts,
                                              int* __restrict__ offsets,
                                              int* __restrict__ sidx) {
    __shared__ int cnt[C_];
    __shared__ int base[C_];
    __shared__ int cur[C_];
    int bc = blockIdx.x, tid = threadIdx.x;
    for (int i = tid; i < C_; i += 256) { cnt[i] = 0; cur[i] = 0; }
    __syncthreads();
    const int4* g4 = (const int4*)(cl + bc * N_);
    // histogram, int4 reads (N/4 = 1024 int4s, 4 per thread)
    for (int n = tid; n < N_ / 4; n += 256) {
        int4 c4 = g4[n];
        atomicAdd(&cnt[c4.x], 1);
        atomicAdd(&cnt[c4.y], 1);
        atomicAdd(&cnt[c4.z], 1);
        atomicAdd(&cnt[c4.w], 1);
    }
    __syncthreads();
    // parallel exclusive prefix: thread t sums cnt[0..t) (C is tiny)
    if (tid < C_) {
        int acc = 0;
        for (int i = 0; i < tid; i++) acc += cnt[i];
        base[tid] = acc;
    }
    __syncthreads();
    for (int i = tid; i < C_; i += 256) {
        counts[bc * C_ + i] = (float)cnt[i];
        offsets[bc * (C_ + 1) + i] = base[i];
    }
    if (tid == 0) offsets[bc * (C_ + 1) + C_] = N_;
    // scatter, int4 reads
    for (int n = tid; n < N_ / 4; n += 256) {
        int4 c4 = g4[n];
        int n0 = n * 4;
        sidx[bc * N_ + base[c4.x] + atomicAdd(&cur[c4.x], 1)] = n0;
        sidx[bc * N_ + base[c4.y] + atomicAdd(&cur[c4.y], 1)] = n0 + 1;
        sidx[bc * N_ + base[c4.z] + atomicAdd(&cur[c4.z], 1)] = n0 + 2;
        sidx[bc * N_ + base[c4.w] + atomicAdd(&cur[c4.w], 1)] = n0 + 3;
    }
}

// ---------------------------------------------------------------- fused segment sums
// One wave per (b, cluster); Q, K, V together: 12 independent 1KB row-gathers
// in flight per iteration (lane = sub*16 + d4). Index loads for iteration i+1
// are issued BEFORE iteration i's data is consumed (software pipeline), so the
// si -> address dependency hides under the outstanding data loads.
// Centers written once, pre-scaled by 1/count. No atomics.
__global__ __launch_bounds__(256) void k_segsum4(const float* __restrict__ q,
                                                 const float* __restrict__ k,
                                                 const float* __restrict__ v,
                                                 const int* __restrict__ offsets,
                                                 const int* __restrict__ sidx,
                                                 float* __restrict__ sums) {
    int bid = blockIdx.x;
    int cg = bid % CG_;
    int b = bid / CG_;
    int wave = threadIdx.x >> 6, lane = threadIdx.x & 63;
    int c = cg * 4 + wave;
    if (c >= C_) return;
    int bc = b & 3;
    int start = offsets[bc * (C_ + 1) + c];
    int end = offsets[bc * (C_ + 1) + c + 1];
    int cnt = end - start;
    int sub = lane >> 4, d4 = lane & 15;

    const float4* q4 = (const float4*)(q + (size_t)b * N_ * D_);
    const float4* k4 = (const float4*)(k + (size_t)b * N_ * D_);
    const float4* v4 = (const float4*)(v + (size_t)b * N_ * D_);
    const int* si = sidx + bc * N_;

    float4 aq = make_float4(0.f, 0.f, 0.f, 0.f);
    float4 ak = make_float4(0.f, 0.f, 0.f, 0.f);
    float4 av = make_float4(0.f, 0.f, 0.f, 0.f);

    if (cnt > 0) {
        int last = end - 1;
        // prologue: indices for iteration 0
        int ia = start + sub, ib = ia + 4, ic = ia + 8, id = ia + 12;
        int ra = si[min(ia, last)], rb = si[min(ib, last)];
        int rc = si[min(ic, last)], rd = si[min(id, last)];
        for (int i0 = start; i0 < end; i0 += 16) {
            int ca = ia, cb = ib, cc = ic, cd = id;
            int ua = ra, ub = rb, uc = rc, ud = rd;
            // prefetch next iteration's indices (independent of data below)
            ia += 16; ib += 16; ic += 16; id += 16;
            if (i0 + 16 < end) {
                ra = si[min(ia, last)]; rb = si[min(ib, last)];
                rc = si[min(ic, last)]; rd = si[min(id, last)];
            }
            float ma = (ca < end) ? 1.f : 0.f;
            float mb = (cb < end) ? 1.f : 0.f;
            float mc = (cc < end) ? 1.f : 0.f;
            float md = (cd < end) ? 1.f : 0.f;
            float4 qa = q4[ua * 16 + d4], qb = q4[ub * 16 + d4];
            float4 qc = q4[uc * 16 + d4], qd = q4[ud * 16 + d4];
            float4 ka = k4[ua * 16 + d4], kb = k4[ub * 16 + d4];
            float4 kc = k4[uc * 16 + d4], kd = k4[ud * 16 + d4];
            float4 va = v4[ua * 16 + d4], vb = v4[ub * 16 + d4];
            float4 vc = v4[uc * 16 + d4], vd = v4[ud * 16 + d4];
            aq.x += ma * qa.x + mb * qb.x + mc * qc.x + md * qd.x;
            aq.y += ma * qa.y + mb * qb.y + mc * qc.y + md * qd.y;
            aq.z += ma * qa.z + mb * qb.z + mc * qc.z + md * qd.z;
            aq.w += ma * qa.w + mb * qb.w + mc * qc.w + md * qd.w;
            ak.x += ma * ka.x + mb * kb.x + mc * kc.x + md * kd.x;
            ak.y += ma * ka.y + mb * kb.y + mc * kc.y + md * kd.y;
            ak.z += ma * ka.z + mb * kb.z + mc * kc.z + md * kd.z;
            ak.w += ma * ka.w + mb * kb.w + mc * kc.w + md * kd.w;
            av.x += ma * va.x + mb * vb.x + mc * vc.x + md * vd.x;
            av.y += ma * va.y + mb * vb.y + mc * vc.y + md * vd.y;
            av.z += ma * va.z + mb * vb.z + mc * vc.z + md * vd.z;
            av.w += ma * va.w + mb * vb.w + mc * vc.w + md * vd.w;
        }
    }
#pragma unroll
    for (int off = 16; off <= 32; off <<= 1) {
        aq.x += __shfl_xor(aq.x, off, 64); aq.y += __shfl_xor(aq.y, off, 64);
        aq.z += __shfl_xor(aq.z, off, 64); aq.w += __shfl_xor(aq.w, off, 64);
        ak.x += __shfl_xor(ak.x, off, 64); ak.y += __shfl_xor(ak.y, off, 64);
        ak.z += __shfl_xor(ak.z, off, 64); ak.w += __shfl_xor(ak.w, off, 64);
        av.x += __shfl_xor(av.x, off, 64); av.y += __shfl_xor(av.y, off, 64);
        av.z += __shfl_xor(av.z, off, 64); av.w += __shfl_xor(av.w, off, 64);
    }
    if (sub == 0) {
        float w = (cnt > 0) ? 1.f / (float)cnt : 0.f;
        float4 oq = make_float4(aq.x * w, aq.y * w, aq.z * w, aq.w * w);
        float4 ok = make_float4(ak.x * w, ak.y * w, ak.z * w, ak.w * w);
        float4 ov = make_float4(av.x * w, av.y * w, av.z * w, av.w * w);
        ((float4*)(sums + (size_t)b * C_ * D_))[c * 16 + d4] = oq;
        ((float4*)(sums + ((size_t)B_ + b) * C_ * D_))[c * 16 + d4] = ok;
        ((float4*)(sums + ((size_t)2 * B_ + b) * C_ * D_))[c * 16 + d4] = ov;
    }
}

// ---------------------------------------------------------------- attention over centers
// grid: B * 9 blocks (16 q-rows per block, last block 1 row). 256 threads.
// Centers arrive pre-scaled by 1/count.
__global__ __launch_bounds__(256) void k_attn(const float* __restrict__ sums,
                                              const float* __restrict__ counts,
                                              float* __restrict__ vout,
                                              float* __restrict__ aout) {
    __shared__ float4 kc4[C_ * 17];   // K centers, 16 data float4 + 1 pad
    __shared__ float4 vc4[C_ * 17];   // V centers
    __shared__ float4 qr4[16 * 16];   // this block's Q rows
    __shared__ float cnt_s[C_];
    __shared__ float arow[4][4][132]; // per-wave A rows (k=0..128, pad to 132)

    int b = blockIdx.x / 9;
    int qg = blockIdx.x % 9;
    int q0 = qg * 16;
    int qcnt = min(16, C_ - q0);
    int tid = threadIdx.x;

    for (int i = tid; i < C_; i += 256)
        cnt_s[i] = counts[(b & 3) * C_ + i];
    __syncthreads();

    const float4* qsum4 = (const float4*)(sums + (size_t)b * C_ * D_);
    const float4* ksum4 = (const float4*)(sums + ((size_t)B_ + b) * C_ * D_);
    const float4* vsum4 = (const float4*)(sums + ((size_t)2 * B_ + b) * C_ * D_);

    for (int i = tid; i < C_ * 16; i += 256) {
        int c = i >> 4, d4 = i & 15;
        kc4[c * 17 + d4] = ksum4[i];
        vc4[c * 17 + d4] = vsum4[i];
    }
    for (int i = tid; i < qcnt * 16; i += 256) {
        int r = i >> 4, d4 = i & 15;
        qr4[i] = qsum4[(q0 + r) * 16 + d4];
    }
    __syncthreads();

    int wave = tid >> 6, lane = tid & 63;

    for (int tt = wave; tt * 4 < qcnt; tt += 4) {
        int t4 = tt * 4;
        // ---- QK: 4 q-rows x (k=lane, k=lane+64, k=128)
        float s0[4] = {0, 0, 0, 0}, s1[4] = {0, 0, 0, 0}, s2[4] = {0, 0, 0, 0};
        for (int d4 = 0; d4 < 16; d4++) {
            float4 kv0 = kc4[lane * 17 + d4];
            float4 kv1 = kc4[(lane + 64) * 17 + d4];
            float4 kv2 = kc4[128 * 17 + d4];
#pragma unroll
            for (int r = 0; r < 4; r++) {
                int rr = t4 + r; if (rr >= qcnt) rr = qcnt - 1;
                float4 qv = qr4[rr * 16 + d4];
                s0[r] += qv.x * kv0.x + qv.y * kv0.y + qv.z * kv0.z + qv.w * kv0.w;
                s1[r] += qv.x * kv1.x + qv.y * kv1.y + qv.z * kv1.z + qv.w * kv1.w;
                s2[r] += qv.x * kv2.x + qv.y * kv2.y + qv.z * kv2.z + qv.w * kv2.w;
            }
        }
        // ---- softmax (weighted by counts, renormalized)
#pragma unroll
        for (int r = 0; r < 4; r++) {
            if (t4 + r >= qcnt) break;
            int qrow = q0 + t4 + r;
            float m = fmaxf(s0[r], s1[r]);
            if (lane == 0) m = fmaxf(m, s2[r]);
            for (int off = 32; off > 0; off >>= 1)
                m = fmaxf(m, __shfl_xor(m, off, 64));
            float e0 = __expf(s0[r] - m) * cnt_s[lane];
            float e1 = __expf(s1[r] - m) * cnt_s[lane + 64];
            float e2 = (lane == 0) ? __expf(s2[r] - m) * cnt_s[128] : 0.f;
            float sum = e0 + e1 + e2;
            for (int off = 32; off > 0; off >>= 1)
                sum += __shfl_xor(sum, off, 64);
            float inv = 1.f / sum;
            float a0 = e0 * inv, a1 = e1 * inv;
            arow[wave][r][lane] = a0;
            arow[wave][r][64 + lane] = a1;
            if (lane == 0) {
                arow[wave][r][128] = e2 * inv;
                aout[b * C_ + qrow] = a0;   // A_full[:, :, 0]
            }
        }
        __builtin_amdgcn_s_waitcnt(0);  // ensure arow writes visible in-wave
        // ---- V product: lane = (row within tile, d4)
        int rr = lane >> 4, d4 = lane & 15;
        const float4* ar4 = (const float4*)arow[wave][rr];
        float4 o = make_float4(0.f, 0.f, 0.f, 0.f);
        for (int k4 = 0; k4 < 32; k4++) {
            float4 a4 = ar4[k4];
            float4 v0 = vc4[(k4 * 4 + 0) * 17 + d4];
            float4 v1 = vc4[(k4 * 4 + 1) * 17 + d4];
            float4 v2 = vc4[(k4 * 4 + 2) * 17 + d4];
            float4 v3 = vc4[(k4 * 4 + 3) * 17 + d4];
            o.x += a4.x * v0.x + a4.y * v1.x + a4.z * v2.x + a4.w * v3.x;
            o.y += a4.x * v0.y + a4.y * v1.y + a4.z * v2.y + a4.w * v3.y;
            o.z += a4.x * v0.z + a4.y * v1.z + a4.z * v2.z + a4.w * v3.z;
            o.w += a4.x * v0.w + a4.y * v1.w + a4.z * v2.w + a4.w * v3.w;
        }
        {
            float a128 = arow[wave][rr][128];
            float4 vv = vc4[128 * 17 + d4];
            o.x += a128 * vv.x; o.y += a128 * vv.y;
            o.z += a128 * vv.z; o.w += a128 * vv.w;
        }
        if (t4 + rr < qcnt) {
            float4* dst = (float4*)(vout + ((size_t)b * C_ + (q0 + t4 + rr)) * D_);
            dst[d4] = o;
        }
    }
}

// ---------------------------------------------------------------- gather
__global__ __launch_bounds__(256) void k_gather(const float* __restrict__ vout,
                                                const int* __restrict__ cl,
                                                float* __restrict__ out) {
    int idx = blockIdx.x * 256 + threadIdx.x;   // over B*N*16 float4s
    int d4 = idx & 15;
    int n = (idx >> 4) & (N_ - 1);
    int b = idx >> 16;
    int c = cl[(b & 3) * N_ + n];
    const float4* src = (const float4*)(vout + ((size_t)b * C_ + c) * D_);
    ((float4*)out)[idx] = src[d4];
}

// ---------------------------------------------------------------- launch
extern "C" void kernel_launch(void* const* d_in, const int* in_sizes, int n_in,
                              void* d_out, int out_size, void* d_ws, size_t ws_size,
                              hipStream_t stream) {
    const float* q = (const float*)d_in[0];
    const float* k = (const float*)d_in[1];
    const float* v = (const float*)d_in[2];
    const int* cl = (const int*)d_in[3];
    float* out = (float*)d_out;
    float* aout = out + (size_t)B_ * N_ * D_;   // A_full[:, :, 0] tail

    float* ws = (float*)d_ws;
    float* counts = ws;                                   // [4][C_] (pad to 1024)
    float* sums = ws + 1024;                              // [3][B_][C_][D_] pre-scaled centers
    float* vout = sums + (size_t)3 * B_ * C_ * D_;        // [B_][C_][D_]
    int* offsets = (int*)(vout + (size_t)B_ * C_ * D_);   // [4][C_+1]
    int* sidx = offsets + 4 * (C_ + 1);                   // [4][N_]

    k_sort<<<BC_, 256, 0, stream>>>(cl, counts, offsets, sidx);
    k_segsum4<<<B_ * CG_, 256, 0, stream>>>(q, k, v, offsets, sidx, sums);
    k_attn<<<B_ * 9, 256, 0, stream>>>(sums, counts, vout, aout);
    k_gather<<<(B_ * N_ * 16) / 256, 256, 0, stream>>>(vout, cl, out);
}